// Round 9
// baseline (77924.738 us; speedup 1.0000x reference)
//
#include <hip/hip_runtime.h>
#include <stdint.h>

// Problem constants
#define NT   8192   // T
#define HID  1024   // H (= I)
#define NWG  128    // persistent workgroups in recurrence

// ---------- f16 helpers (packed 2 x f16 in a uint32: lo = elem0, hi = elem1) ----------
typedef _Float16 f16x2 __attribute__((ext_vector_type(2)));
__device__ __forceinline__ uint32_t f16_bits(float a) {
    return (uint32_t)__builtin_bit_cast(uint16_t, (_Float16)a);
}
__device__ __forceinline__ float f16_lo(uint32_t w) {
    return (float)__builtin_bit_cast(_Float16, (uint16_t)(w & 0xffffu));
}
__device__ __forceinline__ float f16_hi(uint32_t w) {
    return (float)__builtin_bit_cast(_Float16, (uint16_t)(w >> 16));
}
__device__ __forceinline__ uint32_t pack_f16(float a, float b) {
    return f16_bits(a) | (f16_bits(b) << 16);
}
__device__ __forceinline__ float dot2(uint32_t a, uint32_t b, float c) {
    return __builtin_amdgcn_fdot2(__builtin_bit_cast(f16x2, a),
                                  __builtin_bit_cast(f16x2, b), c, false);
}
__device__ __forceinline__ float fast_rcp(float x) { return __builtin_amdgcn_rcpf(x); }
__device__ __forceinline__ float fast_sig(float x) { return fast_rcp(1.f + __expf(-x)); }
__device__ __forceinline__ float fast_tanh(float x) {
    return 1.f - 2.f * fast_rcp(1.f + __expf(2.f * x));
}
__device__ __forceinline__ int tagok8(const uint64_t* x, uint64_t tp) {
    int ok = 1;
#pragma unroll
    for (int m = 0; m < 8; ++m) ok &= ((x[m] & 0xffff0000ffff0000ull) == tp);
    return ok;
}

// ---------- prep: combined bias ----------
__global__ void prep_bias(const float* __restrict__ a, const float* __restrict__ b,
                          float* __restrict__ o) {
    int i = blockIdx.x * 256 + threadIdx.x;
    if (i < 4096) o[i] = a[i] + b[i];
}

// ---------- prep: W_hh -> packed f16, per-WG layout ----------
// Layout: wpk[w][lr][u], lr = wave*8 + gate*2 + jj  <->  row R = gate*1024 + w*8 + 2*wave + jj
// word u packs cols (2u, 2u+1)
__global__ void prep_whh(const float* __restrict__ Whh, uint32_t* __restrict__ wpk) {
    int idx = blockIdx.x * 256 + threadIdx.x;        // 0 .. 128*32*512-1
    int u    = idx & 511;
    int lr   = (idx >> 9) & 31;
    int w    = idx >> 14;
    int v    = lr >> 3;
    int gate = (lr >> 1) & 3;
    int jj   = lr & 1;
    int R = gate * 1024 + w * 8 + 2 * v + jj;
    const float* rp = Whh + (size_t)R * 1024 + 2 * u;
    wpk[idx] = pack_f16(rp[0], rp[1]);
}

// ---------- fp32 tiled GEMM: out[M][N] = A[M][K] @ B[N][K]^T + bias[N] ----------
// 128x128 tile, BK=16, 256 threads, 8x8 microtile. PACK_OUT: write packed f16 pairs.
template <bool PACK_OUT>
__launch_bounds__(256)
__global__ void gemm_bt(const float* __restrict__ A, const float* __restrict__ B,
                        const float* __restrict__ bias, void* __restrict__ outp,
                        int N, int K) {
    __shared__ float As[16 * 132];
    __shared__ float Bs[16 * 132];
    const int tid = threadIdx.x;
    const int bm = blockIdx.x, bn = blockIdx.y;
    const int tx = tid & 15, ty = tid >> 4;
    const int r = tid >> 2, cf = tid & 3;

    float acc[8][8];
#pragma unroll
    for (int i = 0; i < 8; ++i)
#pragma unroll
        for (int j = 0; j < 8; ++j) acc[i][j] = 0.f;

    const float* Ap = A + (size_t)(bm * 128 + r) * K + cf * 4;
    const float* Bp = B + (size_t)(bn * 128 + r) * K + cf * 4;

    for (int k0 = 0; k0 < K; k0 += 16) {
        float4 a0 = *(const float4*)(Ap + k0);
        float4 a1 = *(const float4*)(Ap + (size_t)64 * K + k0);
        float4 b0 = *(const float4*)(Bp + k0);
        float4 b1 = *(const float4*)(Bp + (size_t)64 * K + k0);
        __syncthreads();   // protect previous iteration's LDS reads
#pragma unroll
        for (int e = 0; e < 4; ++e) {
            As[(cf * 4 + e) * 132 + r]      = ((const float*)&a0)[e];
            As[(cf * 4 + e) * 132 + r + 64] = ((const float*)&a1)[e];
            Bs[(cf * 4 + e) * 132 + r]      = ((const float*)&b0)[e];
            Bs[(cf * 4 + e) * 132 + r + 64] = ((const float*)&b1)[e];
        }
        __syncthreads();
#pragma unroll
        for (int k = 0; k < 16; ++k) {
            const float4 av0 = *(const float4*)&As[k * 132 + ty * 8];
            const float4 av1 = *(const float4*)&As[k * 132 + ty * 8 + 4];
            const float4 bv0 = *(const float4*)&Bs[k * 132 + tx * 4];
            const float4 bv1 = *(const float4*)&Bs[k * 132 + tx * 4 + 64];
            const float a[8] = {av0.x, av0.y, av0.z, av0.w, av1.x, av1.y, av1.z, av1.w};
            const float b[8] = {bv0.x, bv0.y, bv0.z, bv0.w, bv1.x, bv1.y, bv1.z, bv1.w};
#pragma unroll
            for (int i = 0; i < 8; ++i)
#pragma unroll
                for (int j = 0; j < 8; ++j) acc[i][j] = fmaf(a[i], b[j], acc[i][j]);
        }
    }

    const int mb = bm * 128 + ty * 8;
    const int n0 = bn * 128 + tx * 4, n1 = n0 + 64;
    float bb[8];
#pragma unroll
    for (int j = 0; j < 4; ++j) { bb[j] = bias[n0 + j]; bb[4 + j] = bias[n1 + j]; }

    if (PACK_OUT) {
        uint32_t* o = (uint32_t*)outp;
        const int halfN = N >> 1;
#pragma unroll
        for (int i = 0; i < 8; ++i) {
            uint2 w0, w1;
            w0.x = pack_f16(acc[i][0] + bb[0], acc[i][1] + bb[1]);
            w0.y = pack_f16(acc[i][2] + bb[2], acc[i][3] + bb[3]);
            w1.x = pack_f16(acc[i][4] + bb[4], acc[i][5] + bb[5]);
            w1.y = pack_f16(acc[i][6] + bb[6], acc[i][7] + bb[7]);
            *(uint2*)(o + (size_t)(mb + i) * halfN + (n0 >> 1)) = w0;
            *(uint2*)(o + (size_t)(mb + i) * halfN + (n1 >> 1)) = w1;
        }
    } else {
        float* o = (float*)outp;
#pragma unroll
        for (int i = 0; i < 8; ++i) {
            float4 v0, v1;
            v0.x = acc[i][0] + bb[0]; v0.y = acc[i][1] + bb[1];
            v0.z = acc[i][2] + bb[2]; v0.w = acc[i][3] + bb[3];
            v1.x = acc[i][4] + bb[4]; v1.y = acc[i][5] + bb[5];
            v1.z = acc[i][6] + bb[6]; v1.w = acc[i][7] + bb[7];
            *(float4*)(o + (size_t)(mb + i) * N + n0) = v0;
            *(float4*)(o + (size_t)(mb + i) * N + n1) = v1;
        }
    }
}

// Reissue one 8-load batch into arr (per-lane exec-masked by the caller's `if`).
#define ISSUE8(arr)                                                         \
    asm volatile(                                                           \
        "global_load_dwordx2 %0, %8, %9\n\t"                                \
        "global_load_dwordx2 %1, %8, %9 offset:512\n\t"                     \
        "global_load_dwordx2 %2, %8, %9 offset:1024\n\t"                    \
        "global_load_dwordx2 %3, %8, %9 offset:1536\n\t"                    \
        "global_load_dwordx2 %4, %8, %9 offset:2048\n\t"                    \
        "global_load_dwordx2 %5, %8, %9 offset:2560\n\t"                    \
        "global_load_dwordx2 %6, %8, %9 offset:3072\n\t"                    \
        "global_load_dwordx2 %7, %8, %9 offset:3584\n\t"                    \
        : "+v"(arr[0]), "+v"(arr[1]), "+v"(arr[2]), "+v"(arr[3]),           \
          "+v"(arr[4]), "+v"(arr[5]), "+v"(arr[6]), "+v"(arr[7])            \
        : "v"(voffh), "s"(srcb)                                             \
        : "memory")

// Wait until only the newest 8-load batch is outstanding; fence scheduling.
#define WAIT8()                                                             \
    do {                                                                    \
        asm volatile("s_waitcnt vmcnt(8)" ::: "memory");                    \
        __builtin_amdgcn_sched_barrier(0);                                  \
    } while (0)

// ---------- persistent LSTM recurrence, barrier-free tagged dataflow ----------
// h word j = (tag<<16) | f16(h_j). H[s] lives in buf[s&1], tagged s. H[0]=tag 0=memset 0.
// Writer of H[s] observed all tags s-1 => every wave finished reading H[s-2] => safe to
// overwrite buf[s&1]. No barriers, no fences, no intra-WG sync in loop.
// 128 WGs x 256 threads; WG w owns units 8w..8w+7; wave v owns units 8w+2v, 8w+2v+1.
// Weights pinned in VGPRs (64 u32/lane). Poll is PIPELINED: two 8-load batches A/B
// alternate with s_waitcnt vmcnt(8), halving the detection quantum vs drain-to-0.
// Correctness: any u64 whose tag matches is valid (tag+value atomic in one load);
// per-lane exec-masked reissues preserve validated regs; VMEM returns in order.
__launch_bounds__(256)
__global__ void lstm_rec(const uint32_t* __restrict__ wpk, const uint32_t* __restrict__ pxp,
                         uint32_t* htag, float* __restrict__ lstm_out) {
    const int tid = threadIdx.x, w = blockIdx.x;
    const int wave = tid >> 6, L = tid & 63;

    // stage this wave's weight slice into VGPRs; keep-alive pins them (opaque to
    // rematerialization, so no stray VMEM loads pollute the vmcnt bookkeeping)
    uint32_t wreg[8][8];
    {
        const uint32_t* wb = wpk + (size_t)w * 16384 + (size_t)(wave * 8) * 512 + L;
#pragma unroll
        for (int rr = 0; rr < 8; ++rr)
#pragma unroll
            for (int m = 0; m < 8; ++m) {
                wreg[rr][m] = wb[rr * 512 + m * 64];
                asm volatile("" : "+v"(wreg[rr][m]));
            }
    }

    float c0 = 0.f;                    // cell state, live only in lanes 0,1 of each wave
    const uint64_t* buf0 = (const uint64_t*)htag;   // 512 u64 (H[even])
    const uint64_t* buf1 = buf0 + 512;              //          (H[odd])
    const uint32_t voffh = (uint32_t)(L * 8);
    const int jbase = w * 8 + 2 * wave;             // unit of lane 0; lane 1 = +1
    uint64_t A[8] = {0, 0, 0, 0, 0, 0, 0, 0};
    uint64_t B[8] = {0, 0, 0, 0, 0, 0, 0, 0};
    int tries = 0;                                  // cumulative tripwire budget

    for (int t = 0; t < NT; ++t) {
        const uint32_t tg = (uint32_t)t;            // tag of H[t]
        const uint64_t* srcb = (t & 1) ? buf1 : buf0;
        uint32_t* dstb = (uint32_t*)((t & 1) ? buf0 : buf1);
        const uint64_t tagpat = ((uint64_t)tg << 16) | ((uint64_t)tg << 48);
        uint32_t vpx  = (uint32_t)t * 8192u + (((uint32_t)(jbase + L)) >> 1) * 4u;
        uint32_t vpx2 = vpx + 4096u;
        uint32_t p0, p1, p2, p3;

        // prologue: px(4) + A(8) + B(8); wait all-but-B (drains leftovers+stores+px+A)
        asm volatile(
            "global_load_dword %16, %22, %24\n\t"
            "global_load_dword %17, %22, %24 offset:2048\n\t"
            "global_load_dword %18, %23, %24\n\t"
            "global_load_dword %19, %23, %24 offset:2048\n\t"
            "global_load_dwordx2 %0, %20, %21\n\t"
            "global_load_dwordx2 %1, %20, %21 offset:512\n\t"
            "global_load_dwordx2 %2, %20, %21 offset:1024\n\t"
            "global_load_dwordx2 %3, %20, %21 offset:1536\n\t"
            "global_load_dwordx2 %4, %20, %21 offset:2048\n\t"
            "global_load_dwordx2 %5, %20, %21 offset:2560\n\t"
            "global_load_dwordx2 %6, %20, %21 offset:3072\n\t"
            "global_load_dwordx2 %7, %20, %21 offset:3584\n\t"
            "global_load_dwordx2 %8, %20, %21\n\t"
            "global_load_dwordx2 %9, %20, %21 offset:512\n\t"
            "global_load_dwordx2 %10, %20, %21 offset:1024\n\t"
            "global_load_dwordx2 %11, %20, %21 offset:1536\n\t"
            "global_load_dwordx2 %12, %20, %21 offset:2048\n\t"
            "global_load_dwordx2 %13, %20, %21 offset:2560\n\t"
            "global_load_dwordx2 %14, %20, %21 offset:3072\n\t"
            "global_load_dwordx2 %15, %20, %21 offset:3584\n\t"
            "s_waitcnt vmcnt(8)"
            : "+v"(A[0]), "+v"(A[1]), "+v"(A[2]), "+v"(A[3]),
              "+v"(A[4]), "+v"(A[5]), "+v"(A[6]), "+v"(A[7]),
              "+v"(B[0]), "+v"(B[1]), "+v"(B[2]), "+v"(B[3]),
              "+v"(B[4]), "+v"(B[5]), "+v"(B[6]), "+v"(B[7]),
              "=&v"(p0), "=&v"(p1), "=&v"(p2), "=&v"(p3)
            : "v"(voffh), "s"(srcb), "v"(vpx), "v"(vpx2), "s"(pxp)
            : "memory");
        __builtin_amdgcn_sched_barrier(0);

        bool selB = false;
        bool mydone = tagok8(A, tagpat) != 0;
        while (!__all(mydone)) {
            if (++tries > (1 << 17)) break;   // cumulative tripwire -> visible failure
            if (!mydone) ISSUE8(A);           // exec-masked: done lanes keep their regs
            WAIT8();                          // B complete
            if (!mydone && tagok8(B, tagpat)) { mydone = true; selB = true; }
            if (__all(mydone)) break;
            if (!mydone) ISSUE8(B);
            WAIT8();                          // A complete
            if (!mydone && tagok8(A, tagpat)) { mydone = true; selB = false; }
        }

        // per-lane select of the validated batch
        uint64_t hp[8];
#pragma unroll
        for (int m = 0; m < 8; ++m) hp[m] = selB ? B[m] : A[m];

        // hk[m] = f16 pair (h[2(L+64m)], h[2(L+64m)+1])
        uint32_t hk[8];
#pragma unroll
        for (int m = 0; m < 8; ++m)
            hk[m] = ((uint32_t)hp[m] & 0xffffu) | (((uint32_t)(hp[m] >> 32)) << 16);

        // 8 row-dots via v_dot2_f32_f16 (rows rr = gate*2 + jj)
        float acc[8];
#pragma unroll
        for (int rr = 0; rr < 8; ++rr) {
            float a = 0.f;
#pragma unroll
            for (int m = 0; m < 8; ++m) a = dot2(wreg[rr][m], hk[m], a);
            acc[rr] = a;
        }

        // folded butterfly over bits {4,2,1}: lane L ends with row (L&7) partial
#pragma unroll
        for (int bit = 4; bit >= 1; bit >>= 1) {
#pragma unroll
            for (int i = 0; i < bit; ++i) {
                float v0 = acc[i], v1 = acc[i + bit];
                float send = (L & bit) ? v0 : v1;
                float recv = __shfl_xor(send, bit, 64);
                acc[i] = ((L & bit) ? v1 : v0) + recv;
            }
        }
        float tot = acc[0];
        tot += __shfl_xor(tot, 8, 64);
        tot += __shfl_xor(tot, 16, 64);
        tot += __shfl_xor(tot, 32, 64);
        // lane jj needs rows jj, 2+jj, 4+jj, 6+jj (held at lanes of those indices)
        float r0 = __shfl(tot, (L & 1), 64);
        float r1 = __shfl(tot, (L & 1) + 2, 64);
        float r2 = __shfl(tot, (L & 1) + 4, 64);
        float r3 = __shfl(tot, (L & 1) + 6, 64);

        // px selection: word held cols (2u,2u+1); lane jj uses lo/hi by (jbase+jj)&1 = jj
        float px0 = (L & 1) ? f16_hi(p0) : f16_lo(p0);
        float px1 = (L & 1) ? f16_hi(p1) : f16_lo(p1);
        float px2 = (L & 1) ? f16_hi(p2) : f16_lo(p2);
        float px3 = (L & 1) ? f16_hi(p3) : f16_lo(p3);

        // elementwise gate update: lanes 0,1 of each wave (jj = L)
        if (L < 2) {
            float gi = r0 + px0;
            float gf = r1 + px1;
            float gg = r2 + px2;
            float go = r3 + px3;
            float iv = fast_sig(gi);
            float fv = fast_sig(gf);
            float gv = fast_tanh(gg);
            float ov = fast_sig(go);
            c0 = fv * c0 + iv * gv;
            float h = ov * fast_tanh(c0);
            int j = jbase + L;
            // publish tagged h FIRST (critical path), then the log
            uint32_t word = f16_bits(h) | ((uint32_t)(t + 1) << 16);
            __hip_atomic_store(dstb + j, word, __ATOMIC_RELAXED, __HIP_MEMORY_SCOPE_AGENT);
            lstm_out[(size_t)t * 1024 + j] = h;
        }
    }
}

// ---------- log-softmax over axis 0 (columns of [8192][512]) ----------
__global__ void sm_partial(const float* __restrict__ logits, float* __restrict__ pM,
                           float* __restrict__ pS) {
    const int cb = blockIdx.x, rb = blockIdx.y, tid = threadIdx.x;
    const int c = cb * 64 + (tid & 63);
    const int r0 = rb * 256 + (tid >> 6) * 64;
    const float* p = logits + (size_t)r0 * 512 + c;
    float m = -1e30f;
    for (int k = 0; k < 64; ++k) m = fmaxf(m, p[(size_t)k * 512]);
    float s = 0.f;
    for (int k = 0; k < 64; ++k) s += __expf(p[(size_t)k * 512] - m);
    __shared__ float sM[4][64], sS[4][64];
    sM[tid >> 6][tid & 63] = m;
    sS[tid >> 6][tid & 63] = s;
    __syncthreads();
    if (tid < 64) {
        float M = sM[0][tid];
        for (int i = 1; i < 4; ++i) M = fmaxf(M, sM[i][tid]);
        float S = 0.f;
        for (int i = 0; i < 4; ++i) S += sS[i][tid] * __expf(sM[i][tid] - M);
        pM[rb * 512 + cb * 64 + tid] = M;
        pS[rb * 512 + cb * 64 + tid] = S;
    }
}

__global__ void sm_combine(const float* __restrict__ pM, const float* __restrict__ pS,
                           float* __restrict__ cc) {
    const int c = threadIdx.x;   // 512 threads
    float M = -1e30f;
    for (int i = 0; i < 32; ++i) M = fmaxf(M, pM[i * 512 + c]);
    float S = 0.f;
    for (int i = 0; i < 32; ++i) S += pS[i * 512 + c] * __expf(pM[i * 512 + c] - M);
    cc[c] = M + logf(S);
}

__global__ void sm_apply(float* __restrict__ out, const float* __restrict__ cc) {
    const int idx = blockIdx.x * 256 + threadIdx.x;    // float4 index, exactly 1M
    float4 v = ((const float4*)out)[idx];
    float4 b = ((const float4*)cc)[idx & 127];
    v.x -= b.x; v.y -= b.y; v.z -= b.z; v.w -= b.w;
    ((float4*)out)[idx] = v;
}

// ---------- launch ----------
extern "C" void kernel_launch(void* const* d_in, const int* in_sizes, int n_in,
                              void* d_out, int out_size, void* d_ws, size_t ws_size,
                              hipStream_t stream) {
    (void)in_sizes; (void)n_in; (void)out_size; (void)ws_size;
    const float* x    = (const float*)d_in[0];
    const float* Wih  = (const float*)d_in[1];
    const float* Whh  = (const float*)d_in[2];
    const float* bih  = (const float*)d_in[3];
    const float* bhh  = (const float*)d_in[4];
    const float* Wout = (const float*)d_in[5];
    const float* bout = (const float*)d_in[6];
    float* out = (float*)d_out;

    char* ws = (char*)d_ws;
    uint32_t* pxp   = (uint32_t*)(ws + 0ull);            // 8192*2048 words   (67,108,864 B)
    uint32_t* wpk   = (uint32_t*)(ws + 67108864ull);     // 128*32*512 words  ( 8,388,608 B)
    float* lstm_out = (float*)   (ws + 75497472ull);     // 8192*1024 f32     (33,554,432 B)
    float* biasc    = (float*)   (ws + 109051904ull);    // 4096 f32 (16 KB)
    uint32_t* htag  = (uint32_t*)(ws + 109068288ull);    // 2*1024 words (8 KB)
    float* pM       = (float*)   (ws + 109076480ull);    // 32*512 f32 (64 KB)
    float* pS       = (float*)   (ws + 109142016ull);    // 32*512 f32 (64 KB)
    float* cc       = (float*)   (ws + 109207552ull);    // 512 f32

    // deterministic per-call state: H[0] = 0 with tag 0
    hipMemsetAsync(htag, 0, 8192, stream);

    prep_whh<<<8192, 256, 0, stream>>>(Whh, wpk);
    prep_bias<<<16, 256, 0, stream>>>(bih, bhh, biasc);

    // px = x @ W_ih^T + (b_ih + b_hh), stored packed f16
    gemm_bt<true><<<dim3(64, 32), 256, 0, stream>>>(x, Wih, biasc, (void*)pxp, 4096, 1024);

    lstm_rec<<<NWG, 256, 0, stream>>>(wpk, pxp, htag, lstm_out);

    // logits = lstm_out @ W_out^T + b_out  -> d_out
    gemm_bt<false><<<dim3(64, 4), 256, 0, stream>>>(lstm_out, Wout, bout, (void*)out, 512, 1024);

    // log-softmax over sequence axis (columns)
    sm_partial<<<dim3(8, 32), 256, 0, stream>>>(out, pM, pS);
    sm_combine<<<1, 512, 0, stream>>>(pM, pS, cc);
    sm_apply<<<4096, 256, 0, stream>>>(out, cc);
}

// Round 11
// 37148.425 us; speedup vs baseline: 2.0977x; 2.0977x over previous
//
#include <hip/hip_runtime.h>
#include <stdint.h>

// Problem constants
#define NT   8192   // T
#define HID  1024   // H (= I)
#define NWG  128    // persistent workgroups in recurrence

// ---------- f16 helpers (packed 2 x f16 in a uint32: lo = elem0, hi = elem1) ----------
typedef _Float16 f16x2 __attribute__((ext_vector_type(2)));
__device__ __forceinline__ uint32_t f16_bits(float a) {
    return (uint32_t)__builtin_bit_cast(uint16_t, (_Float16)a);
}
__device__ __forceinline__ float f16_lo(uint32_t w) {
    return (float)__builtin_bit_cast(_Float16, (uint16_t)(w & 0xffffu));
}
__device__ __forceinline__ float f16_hi(uint32_t w) {
    return (float)__builtin_bit_cast(_Float16, (uint16_t)(w >> 16));
}
__device__ __forceinline__ uint32_t pack_f16(float a, float b) {
    return f16_bits(a) | (f16_bits(b) << 16);
}
__device__ __forceinline__ float dot2(uint32_t a, uint32_t b, float c) {
    return __builtin_amdgcn_fdot2(__builtin_bit_cast(f16x2, a),
                                  __builtin_bit_cast(f16x2, b), c, false);
}
__device__ __forceinline__ float fast_rcp(float x) { return __builtin_amdgcn_rcpf(x); }
__device__ __forceinline__ float fast_sig(float x) { return fast_rcp(1.f + __expf(-x)); }
__device__ __forceinline__ float fast_tanh(float x) {
    return 1.f - 2.f * fast_rcp(1.f + __expf(2.f * x));
}
__device__ __forceinline__ int tagok8(const uint64_t* x, uint64_t tp) {
    int ok = 1;
#pragma unroll
    for (int m = 0; m < 8; ++m) ok &= ((x[m] & 0xffff0000ffff0000ull) == tp);
    return ok;
}

// ---------- prep: combined bias ----------
__global__ void prep_bias(const float* __restrict__ a, const float* __restrict__ b,
                          float* __restrict__ o) {
    int i = blockIdx.x * 256 + threadIdx.x;
    if (i < 4096) o[i] = a[i] + b[i];
}

// ---------- prep: W_hh -> packed f16, per-WG layout ----------
// Layout: wpk[w][lr][u], lr = wave*8 + gate*2 + jj  <->  row R = gate*1024 + w*8 + 2*wave + jj
// word u packs cols (2u, 2u+1)
__global__ void prep_whh(const float* __restrict__ Whh, uint32_t* __restrict__ wpk) {
    int idx = blockIdx.x * 256 + threadIdx.x;        // 0 .. 128*32*512-1
    int u    = idx & 511;
    int lr   = (idx >> 9) & 31;
    int w    = idx >> 14;
    int v    = lr >> 3;
    int gate = (lr >> 1) & 3;
    int jj   = lr & 1;
    int R = gate * 1024 + w * 8 + 2 * v + jj;
    const float* rp = Whh + (size_t)R * 1024 + 2 * u;
    wpk[idx] = pack_f16(rp[0], rp[1]);
}

// ---------- fp32 tiled GEMM: out[M][N] = A[M][K] @ B[N][K]^T + bias[N] ----------
// 128x128 tile, BK=16, 256 threads, 8x8 microtile. PACK_OUT: write packed f16 pairs.
template <bool PACK_OUT>
__launch_bounds__(256)
__global__ void gemm_bt(const float* __restrict__ A, const float* __restrict__ B,
                        const float* __restrict__ bias, void* __restrict__ outp,
                        int N, int K) {
    __shared__ float As[16 * 132];
    __shared__ float Bs[16 * 132];
    const int tid = threadIdx.x;
    const int bm = blockIdx.x, bn = blockIdx.y;
    const int tx = tid & 15, ty = tid >> 4;
    const int r = tid >> 2, cf = tid & 3;

    float acc[8][8];
#pragma unroll
    for (int i = 0; i < 8; ++i)
#pragma unroll
        for (int j = 0; j < 8; ++j) acc[i][j] = 0.f;

    const float* Ap = A + (size_t)(bm * 128 + r) * K + cf * 4;
    const float* Bp = B + (size_t)(bn * 128 + r) * K + cf * 4;

    for (int k0 = 0; k0 < K; k0 += 16) {
        float4 a0 = *(const float4*)(Ap + k0);
        float4 a1 = *(const float4*)(Ap + (size_t)64 * K + k0);
        float4 b0 = *(const float4*)(Bp + k0);
        float4 b1 = *(const float4*)(Bp + (size_t)64 * K + k0);
        __syncthreads();   // protect previous iteration's LDS reads
#pragma unroll
        for (int e = 0; e < 4; ++e) {
            As[(cf * 4 + e) * 132 + r]      = ((const float*)&a0)[e];
            As[(cf * 4 + e) * 132 + r + 64] = ((const float*)&a1)[e];
            Bs[(cf * 4 + e) * 132 + r]      = ((const float*)&b0)[e];
            Bs[(cf * 4 + e) * 132 + r + 64] = ((const float*)&b1)[e];
        }
        __syncthreads();
#pragma unroll
        for (int k = 0; k < 16; ++k) {
            const float4 av0 = *(const float4*)&As[k * 132 + ty * 8];
            const float4 av1 = *(const float4*)&As[k * 132 + ty * 8 + 4];
            const float4 bv0 = *(const float4*)&Bs[k * 132 + tx * 4];
            const float4 bv1 = *(const float4*)&Bs[k * 132 + tx * 4 + 64];
            const float a[8] = {av0.x, av0.y, av0.z, av0.w, av1.x, av1.y, av1.z, av1.w};
            const float b[8] = {bv0.x, bv0.y, bv0.z, bv0.w, bv1.x, bv1.y, bv1.z, bv1.w};
#pragma unroll
            for (int i = 0; i < 8; ++i)
#pragma unroll
                for (int j = 0; j < 8; ++j) acc[i][j] = fmaf(a[i], b[j], acc[i][j]);
        }
    }

    const int mb = bm * 128 + ty * 8;
    const int n0 = bn * 128 + tx * 4, n1 = n0 + 64;
    float bb[8];
#pragma unroll
    for (int j = 0; j < 4; ++j) { bb[j] = bias[n0 + j]; bb[4 + j] = bias[n1 + j]; }

    if (PACK_OUT) {
        uint32_t* o = (uint32_t*)outp;
        const int halfN = N >> 1;
#pragma unroll
        for (int i = 0; i < 8; ++i) {
            uint2 w0, w1;
            w0.x = pack_f16(acc[i][0] + bb[0], acc[i][1] + bb[1]);
            w0.y = pack_f16(acc[i][2] + bb[2], acc[i][3] + bb[3]);
            w1.x = pack_f16(acc[i][4] + bb[4], acc[i][5] + bb[5]);
            w1.y = pack_f16(acc[i][6] + bb[6], acc[i][7] + bb[7]);
            *(uint2*)(o + (size_t)(mb + i) * halfN + (n0 >> 1)) = w0;
            *(uint2*)(o + (size_t)(mb + i) * halfN + (n1 >> 1)) = w1;
        }
    } else {
        float* o = (float*)outp;
#pragma unroll
        for (int i = 0; i < 8; ++i) {
            float4 v0, v1;
            v0.x = acc[i][0] + bb[0]; v0.y = acc[i][1] + bb[1];
            v0.z = acc[i][2] + bb[2]; v0.w = acc[i][3] + bb[3];
            v1.x = acc[i][4] + bb[4]; v1.y = acc[i][5] + bb[5];
            v1.z = acc[i][6] + bb[6]; v1.w = acc[i][7] + bb[7];
            *(float4*)(o + (size_t)(mb + i) * N + n0) = v0;
            *(float4*)(o + (size_t)(mb + i) * N + n1) = v1;
        }
    }
}

// Reissue one 8-load batch into arr (per-lane exec-masked by the caller's `if`).
// sc0 sc1 = bypass non-coherent L1 + per-XCD L2 (same scope bits as agent atomic load);
// without them the poll spins on a stale L1 line forever (round 9/10 failure).
#define ISSUE8(arr)                                                         \
    asm volatile(                                                           \
        "global_load_dwordx2 %0, %8, %9 sc0 sc1\n\t"                        \
        "global_load_dwordx2 %1, %8, %9 offset:512 sc0 sc1\n\t"             \
        "global_load_dwordx2 %2, %8, %9 offset:1024 sc0 sc1\n\t"            \
        "global_load_dwordx2 %3, %8, %9 offset:1536 sc0 sc1\n\t"            \
        "global_load_dwordx2 %4, %8, %9 offset:2048 sc0 sc1\n\t"            \
        "global_load_dwordx2 %5, %8, %9 offset:2560 sc0 sc1\n\t"            \
        "global_load_dwordx2 %6, %8, %9 offset:3072 sc0 sc1\n\t"            \
        "global_load_dwordx2 %7, %8, %9 offset:3584 sc0 sc1\n\t"            \
        : "+v"(arr[0]), "+v"(arr[1]), "+v"(arr[2]), "+v"(arr[3]),           \
          "+v"(arr[4]), "+v"(arr[5]), "+v"(arr[6]), "+v"(arr[7])            \
        : "v"(voffh), "s"(srcb)                                             \
        : "memory")

// Wait until only the newest 8-load batch is outstanding; fence scheduling.
#define WAIT8()                                                             \
    do {                                                                    \
        asm volatile("s_waitcnt vmcnt(8)" ::: "memory");                    \
        __builtin_amdgcn_sched_barrier(0);                                  \
    } while (0)

// ---------- persistent LSTM recurrence, barrier-free tagged dataflow ----------
// h word j = (tag<<16) | f16(h_j). H[s] lives in buf[s&1], tagged s. H[0]=tag 0=memset 0.
// Writer of H[s] observed all tags s-1 => every wave finished reading H[s-2] => safe to
// overwrite buf[s&1]. No barriers, no fences, no intra-WG sync in loop.
// 128 WGs x 256 threads; WG w owns units 8w..8w+7; wave v owns units 8w+2v, 8w+2v+1.
// Weights pinned in VGPRs (64 u32/lane). Poll is PIPELINED: two 8-load batches A/B
// alternate with s_waitcnt vmcnt(8), halving the detection quantum vs drain-to-0.
// Correctness: tag+value atomic per u64 load; per-lane exec-masked reissues preserve
// validated regs; VMEM returns are in-order per wave, and A/B stay live across the
// iteration (next prologue's "+v"), so in-flight returns can never clobber reused regs.
// __launch_bounds__(256,1): 128 WGs on 256 CUs -> occupancy moot; lift VGPR cap so
// wreg+A+B (~130 VGPRs) stay in registers (round 9's 68-VGPR cap caused scratch spills).
// Dual tripwire (per-step 2^11, cumulative 2^17): a broken exchange costs <1 s/call and
// fails visibly on absmax instead of timing out.
__launch_bounds__(256, 1)
__global__ void lstm_rec(const uint32_t* __restrict__ wpk, const uint32_t* __restrict__ pxp,
                         uint32_t* htag, float* __restrict__ lstm_out) {
    const int tid = threadIdx.x, w = blockIdx.x;
    const int wave = tid >> 6, L = tid & 63;

    // stage this wave's weight slice into VGPRs; keep-alive pins them (opaque to
    // rematerialization, so no stray VMEM loads pollute the vmcnt bookkeeping)
    uint32_t wreg[8][8];
    {
        const uint32_t* wb = wpk + (size_t)w * 16384 + (size_t)(wave * 8) * 512 + L;
#pragma unroll
        for (int rr = 0; rr < 8; ++rr)
#pragma unroll
            for (int m = 0; m < 8; ++m) {
                wreg[rr][m] = wb[rr * 512 + m * 64];
                asm volatile("" : "+v"(wreg[rr][m]));
            }
    }

    float c0 = 0.f;                    // cell state, live only in lanes 0,1 of each wave
    const uint64_t* buf0 = (const uint64_t*)htag;   // 512 u64 (H[even])
    const uint64_t* buf1 = buf0 + 512;              //          (H[odd])
    const uint32_t voffh = (uint32_t)(L * 8);
    const int jbase = w * 8 + 2 * wave;             // unit of lane 0; lane 1 = +1
    uint64_t A[8] = {0, 0, 0, 0, 0, 0, 0, 0};
    uint64_t B[8] = {0, 0, 0, 0, 0, 0, 0, 0};
    int tw = 0;                                     // cumulative tripwire budget

    for (int t = 0; t < NT; ++t) {
        const uint32_t tg = (uint32_t)t;            // tag of H[t]
        const uint64_t* srcb = (t & 1) ? buf1 : buf0;
        uint32_t* dstb = (uint32_t*)((t & 1) ? buf0 : buf1);
        const uint64_t tagpat = ((uint64_t)tg << 16) | ((uint64_t)tg << 48);
        uint32_t vpx  = (uint32_t)t * 8192u + (((uint32_t)(jbase + (L & 1))) >> 1) * 4u;
        uint32_t vpx2 = vpx + 4096u;
        uint32_t p0, p1, p2, p3;

        // prologue: px(4) + A(8 sc0sc1) + B(8 sc0sc1); wait all-but-B
        // (drains leftovers + publish stores + px + A)
        asm volatile(
            "global_load_dword %16, %22, %24\n\t"
            "global_load_dword %17, %22, %24 offset:2048\n\t"
            "global_load_dword %18, %23, %24\n\t"
            "global_load_dword %19, %23, %24 offset:2048\n\t"
            "global_load_dwordx2 %0, %20, %21 sc0 sc1\n\t"
            "global_load_dwordx2 %1, %20, %21 offset:512 sc0 sc1\n\t"
            "global_load_dwordx2 %2, %20, %21 offset:1024 sc0 sc1\n\t"
            "global_load_dwordx2 %3, %20, %21 offset:1536 sc0 sc1\n\t"
            "global_load_dwordx2 %4, %20, %21 offset:2048 sc0 sc1\n\t"
            "global_load_dwordx2 %5, %20, %21 offset:2560 sc0 sc1\n\t"
            "global_load_dwordx2 %6, %20, %21 offset:3072 sc0 sc1\n\t"
            "global_load_dwordx2 %7, %20, %21 offset:3584 sc0 sc1\n\t"
            "global_load_dwordx2 %8, %20, %21 sc0 sc1\n\t"
            "global_load_dwordx2 %9, %20, %21 offset:512 sc0 sc1\n\t"
            "global_load_dwordx2 %10, %20, %21 offset:1024 sc0 sc1\n\t"
            "global_load_dwordx2 %11, %20, %21 offset:1536 sc0 sc1\n\t"
            "global_load_dwordx2 %12, %20, %21 offset:2048 sc0 sc1\n\t"
            "global_load_dwordx2 %13, %20, %21 offset:2560 sc0 sc1\n\t"
            "global_load_dwordx2 %14, %20, %21 offset:3072 sc0 sc1\n\t"
            "global_load_dwordx2 %15, %20, %21 offset:3584 sc0 sc1\n\t"
            "s_waitcnt vmcnt(8)"
            : "+v"(A[0]), "+v"(A[1]), "+v"(A[2]), "+v"(A[3]),
              "+v"(A[4]), "+v"(A[5]), "+v"(A[6]), "+v"(A[7]),
              "+v"(B[0]), "+v"(B[1]), "+v"(B[2]), "+v"(B[3]),
              "+v"(B[4]), "+v"(B[5]), "+v"(B[6]), "+v"(B[7]),
              "=&v"(p0), "=&v"(p1), "=&v"(p2), "=&v"(p3)
            : "v"(voffh), "s"(srcb), "v"(vpx), "v"(vpx2), "s"(pxp)
            : "memory");
        __builtin_amdgcn_sched_barrier(0);

        bool selB = false;
        bool mydone = tagok8(A, tagpat) != 0;
        int tries = 0;                           // per-step budget
        while (!__all(mydone)) {
            if (++tries > (1 << 11)) break;      // stuck step -> bail (visible failure)
            if (tw + tries > (1 << 17)) break;   // cumulative exhaustion -> fast bail
            if (!mydone) ISSUE8(A);              // exec-masked: done lanes keep regs
            WAIT8();                             // B complete
            if (!mydone && tagok8(B, tagpat)) { mydone = true; selB = true; }
            if (__all(mydone)) break;
            if (!mydone) ISSUE8(B);
            WAIT8();                             // A complete
            if (!mydone && tagok8(A, tagpat)) { mydone = true; selB = false; }
        }
        tw += tries;

        // per-lane select of the validated batch
        uint64_t hp[8];
#pragma unroll
        for (int m = 0; m < 8; ++m) hp[m] = selB ? B[m] : A[m];

        // hk[m] = f16 pair (h[2(L+64m)], h[2(L+64m)+1])
        uint32_t hk[8];
#pragma unroll
        for (int m = 0; m < 8; ++m)
            hk[m] = ((uint32_t)hp[m] & 0xffffu) | (((uint32_t)(hp[m] >> 32)) << 16);

        // 8 row-dots via v_dot2_f32_f16 (rows rr = gate*2 + jj)
        float acc[8];
#pragma unroll
        for (int rr = 0; rr < 8; ++rr) {
            float a = 0.f;
#pragma unroll
            for (int m = 0; m < 8; ++m) a = dot2(wreg[rr][m], hk[m], a);
            acc[rr] = a;
        }

        // folded butterfly over bits {4,2,1}: lane L ends with row (L&7) partial
#pragma unroll
        for (int bit = 4; bit >= 1; bit >>= 1) {
#pragma unroll
            for (int i = 0; i < bit; ++i) {
                float v0 = acc[i], v1 = acc[i + bit];
                float send = (L & bit) ? v0 : v1;
                float recv = __shfl_xor(send, bit, 64);
                acc[i] = ((L & bit) ? v1 : v0) + recv;
            }
        }
        float tot = acc[0];
        tot += __shfl_xor(tot, 8, 64);
        tot += __shfl_xor(tot, 16, 64);
        tot += __shfl_xor(tot, 32, 64);
        // lane jj needs rows jj, 2+jj, 4+jj, 6+jj (held at lanes of those indices)
        float r0 = __shfl(tot, (L & 1), 64);
        float r1 = __shfl(tot, (L & 1) + 2, 64);
        float r2 = __shfl(tot, (L & 1) + 4, 64);
        float r3 = __shfl(tot, (L & 1) + 6, 64);

        // px selection: word held cols (2u,2u+1); lane jj uses lo/hi by (jbase+jj)&1 = jj
        float px0 = (L & 1) ? f16_hi(p0) : f16_lo(p0);
        float px1 = (L & 1) ? f16_hi(p1) : f16_lo(p1);
        float px2 = (L & 1) ? f16_hi(p2) : f16_lo(p2);
        float px3 = (L & 1) ? f16_hi(p3) : f16_lo(p3);

        // elementwise gate update: lanes 0,1 of each wave (jj = L)
        if (L < 2) {
            float gi = r0 + px0;
            float gf = r1 + px1;
            float gg = r2 + px2;
            float go = r3 + px3;
            float iv = fast_sig(gi);
            float fv = fast_sig(gf);
            float gv = fast_tanh(gg);
            float ov = fast_sig(go);
            c0 = fv * c0 + iv * gv;
            float h = ov * fast_tanh(c0);
            int j = jbase + L;
            // publish tagged h FIRST (critical path), then the log
            uint32_t word = f16_bits(h) | ((uint32_t)(t + 1) << 16);
            __hip_atomic_store(dstb + j, word, __ATOMIC_RELAXED, __HIP_MEMORY_SCOPE_AGENT);
            lstm_out[(size_t)t * 1024 + j] = h;
        }
    }
}

// ---------- log-softmax over axis 0 (columns of [8192][512]) ----------
__global__ void sm_partial(const float* __restrict__ logits, float* __restrict__ pM,
                           float* __restrict__ pS) {
    const int cb = blockIdx.x, rb = blockIdx.y, tid = threadIdx.x;
    const int c = cb * 64 + (tid & 63);
    const int r0 = rb * 256 + (tid >> 6) * 64;
    const float* p = logits + (size_t)r0 * 512 + c;
    float m = -1e30f;
    for (int k = 0; k < 64; ++k) m = fmaxf(m, p[(size_t)k * 512]);
    float s = 0.f;
    for (int k = 0; k < 64; ++k) s += __expf(p[(size_t)k * 512] - m);
    __shared__ float sM[4][64], sS[4][64];
    sM[tid >> 6][tid & 63] = m;
    sS[tid >> 6][tid & 63] = s;
    __syncthreads();
    if (tid < 64) {
        float M = sM[0][tid];
        for (int i = 1; i < 4; ++i) M = fmaxf(M, sM[i][tid]);
        float S = 0.f;
        for (int i = 0; i < 4; ++i) S += sS[i][tid] * __expf(sM[i][tid] - M);
        pM[rb * 512 + cb * 64 + tid] = M;
        pS[rb * 512 + cb * 64 + tid] = S;
    }
}

__global__ void sm_combine(const float* __restrict__ pM, const float* __restrict__ pS,
                           float* __restrict__ cc) {
    const int c = threadIdx.x;   // 512 threads
    float M = -1e30f;
    for (int i = 0; i < 32; ++i) M = fmaxf(M, pM[i * 512 + c]);
    float S = 0.f;
    for (int i = 0; i < 32; ++i) S += pS[i * 512 + c] * __expf(pM[i * 512 + c] - M);
    cc[c] = M + logf(S);
}

__global__ void sm_apply(float* __restrict__ out, const float* __restrict__ cc) {
    const int idx = blockIdx.x * 256 + threadIdx.x;    // float4 index, exactly 1M
    float4 v = ((const float4*)out)[idx];
    float4 b = ((const float4*)cc)[idx & 127];
    v.x -= b.x; v.y -= b.y; v.z -= b.z; v.w -= b.w;
    ((float4*)out)[idx] = v;
}

// ---------- launch ----------
extern "C" void kernel_launch(void* const* d_in, const int* in_sizes, int n_in,
                              void* d_out, int out_size, void* d_ws, size_t ws_size,
                              hipStream_t stream) {
    (void)in_sizes; (void)n_in; (void)out_size; (void)ws_size;
    const float* x    = (const float*)d_in[0];
    const float* Wih  = (const float*)d_in[1];
    const float* Whh  = (const float*)d_in[2];
    const float* bih  = (const float*)d_in[3];
    const float* bhh  = (const float*)d_in[4];
    const float* Wout = (const float*)d_in[5];
    const float* bout = (const float*)d_in[6];
    float* out = (float*)d_out;

    char* ws = (char*)d_ws;
    uint32_t* pxp   = (uint32_t*)(ws + 0ull);            // 8192*2048 words   (67,108,864 B)
    uint32_t* wpk   = (uint32_t*)(ws + 67108864ull);     // 128*32*512 words  ( 8,388,608 B)
    float* lstm_out = (float*)   (ws + 75497472ull);     // 8192*1024 f32     (33,554,432 B)
    float* biasc    = (float*)   (ws + 109051904ull);    // 4096 f32 (16 KB)
    uint32_t* htag  = (uint32_t*)(ws + 109068288ull);    // 2*1024 words (8 KB)
    float* pM       = (float*)   (ws + 109076480ull);    // 32*512 f32 (64 KB)
    float* pS       = (float*)   (ws + 109142016ull);    // 32*512 f32 (64 KB)
    float* cc       = (float*)   (ws + 109207552ull);    // 512 f32

    // deterministic per-call state: H[0] = 0 with tag 0
    hipMemsetAsync(htag, 0, 8192, stream);

    prep_whh<<<8192, 256, 0, stream>>>(Whh, wpk);
    prep_bias<<<16, 256, 0, stream>>>(bih, bhh, biasc);

    // px = x @ W_ih^T + (b_ih + b_hh), stored packed f16
    gemm_bt<true><<<dim3(64, 32), 256, 0, stream>>>(x, Wih, biasc, (void*)pxp, 4096, 1024);

    lstm_rec<<<NWG, 256, 0, stream>>>(wpk, pxp, htag, lstm_out);

    // logits = lstm_out @ W_out^T + b_out  -> d_out
    gemm_bt<false><<<dim3(64, 4), 256, 0, stream>>>(lstm_out, Wout, bout, (void*)out, 512, 1024);

    // log-softmax over sequence axis (columns)
    sm_partial<<<dim3(8, 32), 256, 0, stream>>>(out, pM, pS);
    sm_combine<<<1, 512, 0, stream>>>(pM, pS, cc);
    sm_apply<<<4096, 256, 0, stream>>>(out, cc);
}

// Round 12
// 14757.471 us; speedup vs baseline: 5.2804x; 2.5173x over previous
//
#include <hip/hip_runtime.h>
#include <stdint.h>

// Problem constants
#define NT   8192   // T
#define HID  1024   // H (= I)
#define NWG  128    // persistent workgroups in recurrence

// ---------- f16 helpers (packed 2 x f16 in a uint32: lo = elem0, hi = elem1) ----------
typedef _Float16 f16x2 __attribute__((ext_vector_type(2)));
__device__ __forceinline__ uint32_t f16_bits(float a) {
    return (uint32_t)__builtin_bit_cast(uint16_t, (_Float16)a);
}
__device__ __forceinline__ float f16_lo(uint32_t w) {
    return (float)__builtin_bit_cast(_Float16, (uint16_t)(w & 0xffffu));
}
__device__ __forceinline__ float f16_hi(uint32_t w) {
    return (float)__builtin_bit_cast(_Float16, (uint16_t)(w >> 16));
}
__device__ __forceinline__ uint32_t pack_f16(float a, float b) {
    return f16_bits(a) | (f16_bits(b) << 16);
}
__device__ __forceinline__ float dot2(uint32_t a, uint32_t b, float c) {
    return __builtin_amdgcn_fdot2(__builtin_bit_cast(f16x2, a),
                                  __builtin_bit_cast(f16x2, b), c, false);
}
__device__ __forceinline__ float fast_rcp(float x) { return __builtin_amdgcn_rcpf(x); }
__device__ __forceinline__ float fast_sig(float x) { return fast_rcp(1.f + __expf(-x)); }
__device__ __forceinline__ float fast_tanh(float x) {
    return 1.f - 2.f * fast_rcp(1.f + __expf(2.f * x));
}

// ---------- prep: combined bias ----------
__global__ void prep_bias(const float* __restrict__ a, const float* __restrict__ b,
                          float* __restrict__ o) {
    int i = blockIdx.x * 256 + threadIdx.x;
    if (i < 4096) o[i] = a[i] + b[i];
}

// ---------- prep: W_hh -> packed f16, per-WG layout ----------
// Layout: wpk[w][lr][u], lr = wave*8 + gate*2 + jj  <->  row R = gate*1024 + w*8 + 2*wave + jj
// word u packs cols (2u, 2u+1)
__global__ void prep_whh(const float* __restrict__ Whh, uint32_t* __restrict__ wpk) {
    int idx = blockIdx.x * 256 + threadIdx.x;        // 0 .. 128*32*512-1
    int u    = idx & 511;
    int lr   = (idx >> 9) & 31;
    int w    = idx >> 14;
    int v    = lr >> 3;
    int gate = (lr >> 1) & 3;
    int jj   = lr & 1;
    int R = gate * 1024 + w * 8 + 2 * v + jj;
    const float* rp = Whh + (size_t)R * 1024 + 2 * u;
    wpk[idx] = pack_f16(rp[0], rp[1]);
}

// ---------- fp32 tiled GEMM: out[M][N] = A[M][K] @ B[N][K]^T + bias[N] ----------
// 128x128 tile, BK=16, 256 threads, 8x8 microtile. PACK_OUT: write packed f16 pairs.
template <bool PACK_OUT>
__launch_bounds__(256)
__global__ void gemm_bt(const float* __restrict__ A, const float* __restrict__ B,
                        const float* __restrict__ bias, void* __restrict__ outp,
                        int N, int K) {
    __shared__ float As[16 * 132];
    __shared__ float Bs[16 * 132];
    const int tid = threadIdx.x;
    const int bm = blockIdx.x, bn = blockIdx.y;
    const int tx = tid & 15, ty = tid >> 4;
    const int r = tid >> 2, cf = tid & 3;

    float acc[8][8];
#pragma unroll
    for (int i = 0; i < 8; ++i)
#pragma unroll
        for (int j = 0; j < 8; ++j) acc[i][j] = 0.f;

    const float* Ap = A + (size_t)(bm * 128 + r) * K + cf * 4;
    const float* Bp = B + (size_t)(bn * 128 + r) * K + cf * 4;

    for (int k0 = 0; k0 < K; k0 += 16) {
        float4 a0 = *(const float4*)(Ap + k0);
        float4 a1 = *(const float4*)(Ap + (size_t)64 * K + k0);
        float4 b0 = *(const float4*)(Bp + k0);
        float4 b1 = *(const float4*)(Bp + (size_t)64 * K + k0);
        __syncthreads();   // protect previous iteration's LDS reads
#pragma unroll
        for (int e = 0; e < 4; ++e) {
            As[(cf * 4 + e) * 132 + r]      = ((const float*)&a0)[e];
            As[(cf * 4 + e) * 132 + r + 64] = ((const float*)&a1)[e];
            Bs[(cf * 4 + e) * 132 + r]      = ((const float*)&b0)[e];
            Bs[(cf * 4 + e) * 132 + r + 64] = ((const float*)&b1)[e];
        }
        __syncthreads();
#pragma unroll
        for (int k = 0; k < 16; ++k) {
            const float4 av0 = *(const float4*)&As[k * 132 + ty * 8];
            const float4 av1 = *(const float4*)&As[k * 132 + ty * 8 + 4];
            const float4 bv0 = *(const float4*)&Bs[k * 132 + tx * 4];
            const float4 bv1 = *(const float4*)&Bs[k * 132 + tx * 4 + 64];
            const float a[8] = {av0.x, av0.y, av0.z, av0.w, av1.x, av1.y, av1.z, av1.w};
            const float b[8] = {bv0.x, bv0.y, bv0.z, bv0.w, bv1.x, bv1.y, bv1.z, bv1.w};
#pragma unroll
            for (int i = 0; i < 8; ++i)
#pragma unroll
                for (int j = 0; j < 8; ++j) acc[i][j] = fmaf(a[i], b[j], acc[i][j]);
        }
    }

    const int mb = bm * 128 + ty * 8;
    const int n0 = bn * 128 + tx * 4, n1 = n0 + 64;
    float bb[8];
#pragma unroll
    for (int j = 0; j < 4; ++j) { bb[j] = bias[n0 + j]; bb[4 + j] = bias[n1 + j]; }

    if (PACK_OUT) {
        uint32_t* o = (uint32_t*)outp;
        const int halfN = N >> 1;
#pragma unroll
        for (int i = 0; i < 8; ++i) {
            uint2 w0, w1;
            w0.x = pack_f16(acc[i][0] + bb[0], acc[i][1] + bb[1]);
            w0.y = pack_f16(acc[i][2] + bb[2], acc[i][3] + bb[3]);
            w1.x = pack_f16(acc[i][4] + bb[4], acc[i][5] + bb[5]);
            w1.y = pack_f16(acc[i][6] + bb[6], acc[i][7] + bb[7]);
            *(uint2*)(o + (size_t)(mb + i) * halfN + (n0 >> 1)) = w0;
            *(uint2*)(o + (size_t)(mb + i) * halfN + (n1 >> 1)) = w1;
        }
    } else {
        float* o = (float*)outp;
#pragma unroll
        for (int i = 0; i < 8; ++i) {
            float4 v0, v1;
            v0.x = acc[i][0] + bb[0]; v0.y = acc[i][1] + bb[1];
            v0.z = acc[i][2] + bb[2]; v0.w = acc[i][3] + bb[3];
            v1.x = acc[i][4] + bb[4]; v1.y = acc[i][5] + bb[5];
            v1.z = acc[i][6] + bb[6]; v1.w = acc[i][7] + bb[7];
            *(float4*)(o + (size_t)(mb + i) * N + n0) = v0;
            *(float4*)(o + (size_t)(mb + i) * N + n1) = v1;
        }
    }
}

// ---------- persistent LSTM recurrence, tagged dataflow + intra-WG poll division ----------
// h word j = (tag<<16) | f16(h_j). H[s] lives in buf[s&1], tagged s. H[0]=tag 0=memset 0.
// Writer of H[s] observed all tags s-1 => every wave finished reading H[s-2] => safe to
// overwrite buf[s&1]. 128 WGs x 256 threads; WG w owns units 8w..8w+7; wave v owns units
// 8w+2v, 8w+2v+1. Weights in VGPRs (round-8 structure, compiler-managed).
// NEW vs round 8: each wave polls only ITS QUARTER of h (2 u64/lane, contiguous 16B),
// compacts to packed-f16 pairs, stages into parity-double-buffered LDS, one barrier,
// then all lanes read hk[] from LDS. Poll traffic at the coherence point drops 4x
// (round 8: all 4 waves redundantly polled all 64 lines every round -> MALL queueing).
// LDS parity safety: a wave reaches parity-p's next write (step t+2) only after
// validating H[t+1] tags, which requires all waves to have published H[t+1], which
// requires all waves to have read parity-p at step t. Banks: writes 2-way, reads 2-way
// (lane L and L+32 share bank) = free per m136.
__launch_bounds__(256)
__global__ void lstm_rec(const uint32_t* __restrict__ wpk, const uint32_t* __restrict__ pxp,
                         uint32_t* htag, float* __restrict__ lstm_out) {
    __shared__ uint32_t Hl[2][512];   // packed f16 pairs, double-buffered by step parity
    const int tid = threadIdx.x, w = blockIdx.x;
    const int wave = tid >> 6, L = tid & 63;

    // stage this wave's weight slice toward VGPRs (round-8 form)
    uint32_t wreg[8][8];
    {
        const uint32_t* wb = wpk + (size_t)w * 16384 + (size_t)(wave * 8) * 512 + L;
#pragma unroll
        for (int rr = 0; rr < 8; ++rr)
#pragma unroll
            for (int m = 0; m < 8; ++m)
                wreg[rr][m] = wb[rr * 512 + m * 64];
    }

    float c0 = 0.f;                    // cell state, live only in lanes 0,1 of each wave
    const uint64_t* buf0 = (const uint64_t*)htag;   // 512 u64 (H[even])
    const uint64_t* buf1 = buf0 + 512;              //          (H[odd])
    const int q0 = 128 * wave + 2 * L;              // this lane's quarter-poll u64 index
    int tw = 0;                                     // cumulative tripwire

    for (int t = 0; t < NT; ++t) {
        const uint32_t tg = (uint32_t)t;            // tag of H[t]
        const uint64_t* srcb = (t & 1) ? buf1 : buf0;
        uint32_t* dstb = (uint32_t*)((t & 1) ? buf0 : buf1);
        const uint64_t tagpat = ((uint64_t)tg << 16) | ((uint64_t)tg << 48);

        // px for my gates — issued before the poll so the latency hides under it
        float pxv[4] = {0.f, 0.f, 0.f, 0.f};
        if (L < 2) {
#pragma unroll
            for (int g = 0; g < 4; ++g) {
                int R = g * 1024 + w * 8 + 2 * wave + L;
                uint32_t pw = pxp[(size_t)t * 2048 + (R >> 1)];
                pxv[g] = (R & 1) ? f16_hi(pw) : f16_lo(pw);
            }
        }

        // quarter poll: lane validates u64 q0, q0+1 (one 16B region); done lanes skip
        uint64_t ha = 0, hb = 0;
        bool done = false;
        int tries = 0;
        for (;;) {
            if (!done) {
                ha = __hip_atomic_load(srcb + q0,     __ATOMIC_RELAXED,
                                       __HIP_MEMORY_SCOPE_AGENT);
                hb = __hip_atomic_load(srcb + q0 + 1, __ATOMIC_RELAXED,
                                       __HIP_MEMORY_SCOPE_AGENT);
                done = ((ha & 0xffff0000ffff0000ull) == tagpat) &
                       ((hb & 0xffff0000ffff0000ull) == tagpat);
            }
            if (__all(done)) break;
            if (++tries > (1 << 13) || tw + tries > (1 << 17)) break;  // visible failure
        }
        tw += tries;

        // compact (strip tags) and stage into LDS
        uint32_t* Hb = Hl[t & 1];
        Hb[q0]     = ((uint32_t)ha & 0xffffu) | (((uint32_t)(ha >> 32)) << 16);
        Hb[q0 + 1] = ((uint32_t)hb & 0xffffu) | (((uint32_t)(hb >> 32)) << 16);
        __syncthreads();

        // hk[m] = packed f16 pair (h[2(L+64m)], h[2(L+64m)+1])
        uint32_t hk[8];
#pragma unroll
        for (int m = 0; m < 8; ++m) hk[m] = Hb[L + 64 * m];

        // 8 row-dots via v_dot2_f32_f16 (rows rr = gate*2 + jj)
        float acc[8];
#pragma unroll
        for (int rr = 0; rr < 8; ++rr) {
            float a = 0.f;
#pragma unroll
            for (int m = 0; m < 8; ++m) a = dot2(wreg[rr][m], hk[m], a);
            acc[rr] = a;
        }

        // folded butterfly over bits {4,2,1}: lane L ends with row (L&7) partial
#pragma unroll
        for (int bit = 4; bit >= 1; bit >>= 1) {
#pragma unroll
            for (int i = 0; i < bit; ++i) {
                float v0 = acc[i], v1 = acc[i + bit];
                float send = (L & bit) ? v0 : v1;
                float recv = __shfl_xor(send, bit, 64);
                acc[i] = ((L & bit) ? v1 : v0) + recv;
            }
        }
        float tot = acc[0];
        tot += __shfl_xor(tot, 8, 64);
        tot += __shfl_xor(tot, 16, 64);
        tot += __shfl_xor(tot, 32, 64);
        // lane jj needs rows jj, 2+jj, 4+jj, 6+jj (held at lanes of those indices)
        float r0 = __shfl(tot, (L & 1), 64);
        float r1 = __shfl(tot, (L & 1) + 2, 64);
        float r2 = __shfl(tot, (L & 1) + 4, 64);
        float r3 = __shfl(tot, (L & 1) + 6, 64);

        // elementwise gate update: lanes 0,1 of each wave (jj = L)
        if (L < 2) {
            float gi = r0 + pxv[0];
            float gf = r1 + pxv[1];
            float gg = r2 + pxv[2];
            float go = r3 + pxv[3];
            float iv = fast_sig(gi);
            float fv = fast_sig(gf);
            float gv = fast_tanh(gg);
            float ov = fast_sig(go);
            c0 = fv * c0 + iv * gv;
            float h = ov * fast_tanh(c0);
            int j = w * 8 + 2 * wave + L;
            // publish tagged h FIRST (critical path), then the log
            uint32_t word = f16_bits(h) | ((uint32_t)(t + 1) << 16);
            __hip_atomic_store(dstb + j, word, __ATOMIC_RELAXED, __HIP_MEMORY_SCOPE_AGENT);
            lstm_out[(size_t)t * 1024 + j] = h;
        }
    }
}

// ---------- log-softmax over axis 0 (columns of [8192][512]) ----------
__global__ void sm_partial(const float* __restrict__ logits, float* __restrict__ pM,
                           float* __restrict__ pS) {
    const int cb = blockIdx.x, rb = blockIdx.y, tid = threadIdx.x;
    const int c = cb * 64 + (tid & 63);
    const int r0 = rb * 256 + (tid >> 6) * 64;
    const float* p = logits + (size_t)r0 * 512 + c;
    float m = -1e30f;
    for (int k = 0; k < 64; ++k) m = fmaxf(m, p[(size_t)k * 512]);
    float s = 0.f;
    for (int k = 0; k < 64; ++k) s += __expf(p[(size_t)k * 512] - m);
    __shared__ float sM[4][64], sS[4][64];
    sM[tid >> 6][tid & 63] = m;
    sS[tid >> 6][tid & 63] = s;
    __syncthreads();
    if (tid < 64) {
        float M = sM[0][tid];
        for (int i = 1; i < 4; ++i) M = fmaxf(M, sM[i][tid]);
        float S = 0.f;
        for (int i = 0; i < 4; ++i) S += sS[i][tid] * __expf(sM[i][tid] - M);
        pM[rb * 512 + cb * 64 + tid] = M;
        pS[rb * 512 + cb * 64 + tid] = S;
    }
}

__global__ void sm_combine(const float* __restrict__ pM, const float* __restrict__ pS,
                           float* __restrict__ cc) {
    const int c = threadIdx.x;   // 512 threads
    float M = -1e30f;
    for (int i = 0; i < 32; ++i) M = fmaxf(M, pM[i * 512 + c]);
    float S = 0.f;
    for (int i = 0; i < 32; ++i) S += pS[i * 512 + c] * __expf(pM[i * 512 + c] - M);
    cc[c] = M + logf(S);
}

__global__ void sm_apply(float* __restrict__ out, const float* __restrict__ cc) {
    const int idx = blockIdx.x * 256 + threadIdx.x;    // float4 index, exactly 1M
    float4 v = ((const float4*)out)[idx];
    float4 b = ((const float4*)cc)[idx & 127];
    v.x -= b.x; v.y -= b.y; v.z -= b.z; v.w -= b.w;
    ((float4*)out)[idx] = v;
}

// ---------- launch ----------
extern "C" void kernel_launch(void* const* d_in, const int* in_sizes, int n_in,
                              void* d_out, int out_size, void* d_ws, size_t ws_size,
                              hipStream_t stream) {
    (void)in_sizes; (void)n_in; (void)out_size; (void)ws_size;
    const float* x    = (const float*)d_in[0];
    const float* Wih  = (const float*)d_in[1];
    const float* Whh  = (const float*)d_in[2];
    const float* bih  = (const float*)d_in[3];
    const float* bhh  = (const float*)d_in[4];
    const float* Wout = (const float*)d_in[5];
    const float* bout = (const float*)d_in[6];
    float* out = (float*)d_out;

    char* ws = (char*)d_ws;
    uint32_t* pxp   = (uint32_t*)(ws + 0ull);            // 8192*2048 words   (67,108,864 B)
    uint32_t* wpk   = (uint32_t*)(ws + 67108864ull);     // 128*32*512 words  ( 8,388,608 B)
    float* lstm_out = (float*)   (ws + 75497472ull);     // 8192*1024 f32     (33,554,432 B)
    float* biasc    = (float*)   (ws + 109051904ull);    // 4096 f32 (16 KB)
    uint32_t* htag  = (uint32_t*)(ws + 109068288ull);    // 2*1024 words (8 KB)
    float* pM       = (float*)   (ws + 109076480ull);    // 32*512 f32 (64 KB)
    float* pS       = (float*)   (ws + 109142016ull);    // 32*512 f32 (64 KB)
    float* cc       = (float*)   (ws + 109207552ull);    // 512 f32

    // deterministic per-call state: H[0] = 0 with tag 0
    hipMemsetAsync(htag, 0, 8192, stream);

    prep_whh<<<8192, 256, 0, stream>>>(Whh, wpk);
    prep_bias<<<16, 256, 0, stream>>>(bih, bhh, biasc);

    // px = x @ W_ih^T + (b_ih + b_hh), stored packed f16
    gemm_bt<true><<<dim3(64, 32), 256, 0, stream>>>(x, Wih, biasc, (void*)pxp, 4096, 1024);

    lstm_rec<<<NWG, 256, 0, stream>>>(wpk, pxp, htag, lstm_out);

    // logits = lstm_out @ W_out^T + b_out  -> d_out
    gemm_bt<false><<<dim3(64, 4), 256, 0, stream>>>(lstm_out, Wout, bout, (void*)out, 512, 1024);

    // log-softmax over sequence axis (columns)
    sm_partial<<<dim3(8, 32), 256, 0, stream>>>(out, pM, pS);
    sm_combine<<<1, 512, 0, stream>>>(pM, pS, cc);
    sm_apply<<<4096, 256, 0, stream>>>(out, cc);
}

// Round 13
// 14551.181 us; speedup vs baseline: 5.3552x; 1.0142x over previous
//
#include <hip/hip_runtime.h>
#include <stdint.h>

// Problem constants
#define NT   8192   // T
#define HID  1024   // H (= I)
#define NWG  128    // persistent workgroups in recurrence

// ---------- f16 helpers (packed 2 x f16 in a uint32: lo = elem0, hi = elem1) ----------
typedef _Float16 f16x2 __attribute__((ext_vector_type(2)));
__device__ __forceinline__ uint32_t f16_bits(float a) {
    return (uint32_t)__builtin_bit_cast(uint16_t, (_Float16)a);
}
__device__ __forceinline__ float f16_lo(uint32_t w) {
    return (float)__builtin_bit_cast(_Float16, (uint16_t)(w & 0xffffu));
}
__device__ __forceinline__ float f16_hi(uint32_t w) {
    return (float)__builtin_bit_cast(_Float16, (uint16_t)(w >> 16));
}
__device__ __forceinline__ uint32_t pack_f16(float a, float b) {
    return f16_bits(a) | (f16_bits(b) << 16);
}
__device__ __forceinline__ float dot2(uint32_t a, uint32_t b, float c) {
    return __builtin_amdgcn_fdot2(__builtin_bit_cast(f16x2, a),
                                  __builtin_bit_cast(f16x2, b), c, false);
}
__device__ __forceinline__ float fast_rcp(float x) { return __builtin_amdgcn_rcpf(x); }
__device__ __forceinline__ float fast_sig(float x) { return fast_rcp(1.f + __expf(-x)); }
__device__ __forceinline__ float fast_tanh(float x) {
    return 1.f - 2.f * fast_rcp(1.f + __expf(2.f * x));
}

// ---------- prep: combined bias ----------
__global__ void prep_bias(const float* __restrict__ a, const float* __restrict__ b,
                          float* __restrict__ o) {
    int i = blockIdx.x * 256 + threadIdx.x;
    if (i < 4096) o[i] = a[i] + b[i];
}

// ---------- prep: W_hh -> packed f16, per-WG layout ----------
// Layout: wpk[w][lr][u], lr = wave*8 + gate*2 + jj  <->  row R = gate*1024 + w*8 + 2*wave + jj
// word u packs cols (2u, 2u+1)
__global__ void prep_whh(const float* __restrict__ Whh, uint32_t* __restrict__ wpk) {
    int idx = blockIdx.x * 256 + threadIdx.x;        // 0 .. 128*32*512-1
    int u    = idx & 511;
    int lr   = (idx >> 9) & 31;
    int w    = idx >> 14;
    int v    = lr >> 3;
    int gate = (lr >> 1) & 3;
    int jj   = lr & 1;
    int R = gate * 1024 + w * 8 + 2 * v + jj;
    const float* rp = Whh + (size_t)R * 1024 + 2 * u;
    wpk[idx] = pack_f16(rp[0], rp[1]);
}

// ---------- fp32 tiled GEMM: out[M][N] = A[M][K] @ B[N][K]^T + bias[N] ----------
// 128x128 tile, BK=16, 256 threads, 8x8 microtile. PACK_OUT: write packed f16 pairs.
template <bool PACK_OUT>
__launch_bounds__(256)
__global__ void gemm_bt(const float* __restrict__ A, const float* __restrict__ B,
                        const float* __restrict__ bias, void* __restrict__ outp,
                        int N, int K) {
    __shared__ float As[16 * 132];
    __shared__ float Bs[16 * 132];
    const int tid = threadIdx.x;
    const int bm = blockIdx.x, bn = blockIdx.y;
    const int tx = tid & 15, ty = tid >> 4;
    const int r = tid >> 2, cf = tid & 3;

    float acc[8][8];
#pragma unroll
    for (int i = 0; i < 8; ++i)
#pragma unroll
        for (int j = 0; j < 8; ++j) acc[i][j] = 0.f;

    const float* Ap = A + (size_t)(bm * 128 + r) * K + cf * 4;
    const float* Bp = B + (size_t)(bn * 128 + r) * K + cf * 4;

    for (int k0 = 0; k0 < K; k0 += 16) {
        float4 a0 = *(const float4*)(Ap + k0);
        float4 a1 = *(const float4*)(Ap + (size_t)64 * K + k0);
        float4 b0 = *(const float4*)(Bp + k0);
        float4 b1 = *(const float4*)(Bp + (size_t)64 * K + k0);
        __syncthreads();   // protect previous iteration's LDS reads
#pragma unroll
        for (int e = 0; e < 4; ++e) {
            As[(cf * 4 + e) * 132 + r]      = ((const float*)&a0)[e];
            As[(cf * 4 + e) * 132 + r + 64] = ((const float*)&a1)[e];
            Bs[(cf * 4 + e) * 132 + r]      = ((const float*)&b0)[e];
            Bs[(cf * 4 + e) * 132 + r + 64] = ((const float*)&b1)[e];
        }
        __syncthreads();
#pragma unroll
        for (int k = 0; k < 16; ++k) {
            const float4 av0 = *(const float4*)&As[k * 132 + ty * 8];
            const float4 av1 = *(const float4*)&As[k * 132 + ty * 8 + 4];
            const float4 bv0 = *(const float4*)&Bs[k * 132 + tx * 4];
            const float4 bv1 = *(const float4*)&Bs[k * 132 + tx * 4 + 64];
            const float a[8] = {av0.x, av0.y, av0.z, av0.w, av1.x, av1.y, av1.z, av1.w};
            const float b[8] = {bv0.x, bv0.y, bv0.z, bv0.w, bv1.x, bv1.y, bv1.z, bv1.w};
#pragma unroll
            for (int i = 0; i < 8; ++i)
#pragma unroll
                for (int j = 0; j < 8; ++j) acc[i][j] = fmaf(a[i], b[j], acc[i][j]);
        }
    }

    const int mb = bm * 128 + ty * 8;
    const int n0 = bn * 128 + tx * 4, n1 = n0 + 64;
    float bb[8];
#pragma unroll
    for (int j = 0; j < 4; ++j) { bb[j] = bias[n0 + j]; bb[4 + j] = bias[n1 + j]; }

    if (PACK_OUT) {
        uint32_t* o = (uint32_t*)outp;
        const int halfN = N >> 1;
#pragma unroll
        for (int i = 0; i < 8; ++i) {
            uint2 w0, w1;
            w0.x = pack_f16(acc[i][0] + bb[0], acc[i][1] + bb[1]);
            w0.y = pack_f16(acc[i][2] + bb[2], acc[i][3] + bb[3]);
            w1.x = pack_f16(acc[i][4] + bb[4], acc[i][5] + bb[5]);
            w1.y = pack_f16(acc[i][6] + bb[6], acc[i][7] + bb[7]);
            *(uint2*)(o + (size_t)(mb + i) * halfN + (n0 >> 1)) = w0;
            *(uint2*)(o + (size_t)(mb + i) * halfN + (n1 >> 1)) = w1;
        }
    } else {
        float* o = (float*)outp;
#pragma unroll
        for (int i = 0; i < 8; ++i) {
            float4 v0, v1;
            v0.x = acc[i][0] + bb[0]; v0.y = acc[i][1] + bb[1];
            v0.z = acc[i][2] + bb[2]; v0.w = acc[i][3] + bb[3];
            v1.x = acc[i][4] + bb[4]; v1.y = acc[i][5] + bb[5];
            v1.z = acc[i][6] + bb[6]; v1.w = acc[i][7] + bb[7];
            *(float4*)(o + (size_t)(mb + i) * N + n0) = v0;
            *(float4*)(o + (size_t)(mb + i) * N + n1) = v1;
        }
    }
}

// ---------- persistent LSTM recurrence, tagged dataflow + quarter-poll + 2-deep rotation --
// h word j = (tag<<16) | f16(h_j). H[s] lives in buf[s&1], tagged s. H[0]=tag 0=memset 0.
// Writer of H[s] observed all tags s-1 => every wave finished reading H[s-2] => safe to
// overwrite buf[s&1]. 128 WGs x 256 threads; WG w owns units 8w..8w+7; wave v owns units
// 8w+2v, 8w+2v+1.
// Poll (round-12 division of labor): each wave polls only ITS QUARTER of h (2 u64/lane),
// NEW: with TWO rotating snapshots a/b so one is checked while the other is in flight —
// the backend emits counted vmcnt (not 0) before each check, halving the sampling period.
// Each lane keeps whichever snapshot it validated (tag+value atomic per u64 load).
// Staged to parity-double-buffered LDS, one barrier, all lanes read hk[] from LDS.
// LDS parity safety: a wave reaches parity-p's next write (step t+2) only after
// validating H[t+1] tags, which requires all waves to have published H[t+1], which
// requires all waves to have read parity-p at step t.
// Publish: lane 0 of each wave stores BOTH units' words as one u64 (4 stores/WG).
__launch_bounds__(256)
__global__ void lstm_rec(const uint32_t* __restrict__ wpk, const uint32_t* __restrict__ pxp,
                         uint32_t* htag, float* __restrict__ lstm_out) {
    __shared__ uint32_t Hl[2][512];   // packed f16 pairs, double-buffered by step parity
    const int tid = threadIdx.x, w = blockIdx.x;
    const int wave = tid >> 6, L = tid & 63;

    // stage this wave's weight slice toward VGPRs/L2 (round-8 form)
    uint32_t wreg[8][8];
    {
        const uint32_t* wb = wpk + (size_t)w * 16384 + (size_t)(wave * 8) * 512 + L;
#pragma unroll
        for (int rr = 0; rr < 8; ++rr)
#pragma unroll
            for (int m = 0; m < 8; ++m)
                wreg[rr][m] = wb[rr * 512 + m * 64];
    }

    float c0 = 0.f;                    // cell state, live only in lanes 0,1 of each wave
    const uint64_t* buf0 = (const uint64_t*)htag;   // 512 u64 (H[even])
    const uint64_t* buf1 = buf0 + 512;              //          (H[odd])
    const int q0 = 128 * wave + 2 * L;              // this lane's quarter-poll u64 index
    int tw = 0;                                     // cumulative tripwire

    for (int t = 0; t < NT; ++t) {
        const uint32_t tg = (uint32_t)t;            // tag of H[t]
        const uint64_t* srcb = (t & 1) ? buf1 : buf0;
        uint64_t* dstb = (uint64_t*)((t & 1) ? buf0 : buf1);
        const uint64_t tagpat = ((uint64_t)tg << 16) | ((uint64_t)tg << 48);
        const uint64_t* srcp = srcb + q0;

        // px for my gates — issued before the poll so the latency hides under it
        float pxv[4] = {0.f, 0.f, 0.f, 0.f};
        if (L < 2) {
#pragma unroll
            for (int g = 0; g < 4; ++g) {
                int R = g * 1024 + w * 8 + 2 * wave + L;
                uint32_t pw = pxp[(size_t)t * 2048 + (R >> 1)];
                pxv[g] = (R & 1) ? f16_hi(pw) : f16_lo(pw);
            }
        }

        // 2-deep rotating quarter poll: check snapshot A while B is in flight.
        uint64_t a0, a1, b0, b1;
        a0 = __hip_atomic_load(srcp,     __ATOMIC_RELAXED, __HIP_MEMORY_SCOPE_AGENT);
        a1 = __hip_atomic_load(srcp + 1, __ATOMIC_RELAXED, __HIP_MEMORY_SCOPE_AGENT);
        b0 = __hip_atomic_load(srcp,     __ATOMIC_RELAXED, __HIP_MEMORY_SCOPE_AGENT);
        b1 = __hip_atomic_load(srcp + 1, __ATOMIC_RELAXED, __HIP_MEMORY_SCOPE_AGENT);
        bool done = false, useB = false;
        int tries = 0;
        for (;;) {
            if (!done && ((a0 & 0xffff0000ffff0000ull) == tagpat) &
                         ((a1 & 0xffff0000ffff0000ull) == tagpat)) {
                done = true; useB = false;
            }
            if (__all(done)) break;
            if (!done) {   // reissue A (exec-masked: validated lanes keep snapshots)
                a0 = __hip_atomic_load(srcp,     __ATOMIC_RELAXED, __HIP_MEMORY_SCOPE_AGENT);
                a1 = __hip_atomic_load(srcp + 1, __ATOMIC_RELAXED, __HIP_MEMORY_SCOPE_AGENT);
            }
            if (!done && ((b0 & 0xffff0000ffff0000ull) == tagpat) &
                         ((b1 & 0xffff0000ffff0000ull) == tagpat)) {
                done = true; useB = true;
            }
            if (__all(done)) break;
            if (!done) {
                b0 = __hip_atomic_load(srcp,     __ATOMIC_RELAXED, __HIP_MEMORY_SCOPE_AGENT);
                b1 = __hip_atomic_load(srcp + 1, __ATOMIC_RELAXED, __HIP_MEMORY_SCOPE_AGENT);
            }
            if (++tries > (1 << 13) || tw + tries > (1 << 17)) break;  // visible failure
        }
        tw += tries;
        uint64_t ha = useB ? b0 : a0;
        uint64_t hb = useB ? b1 : a1;

        // compact (strip tags) and stage into LDS
        uint32_t* Hb = Hl[t & 1];
        Hb[q0]     = ((uint32_t)ha & 0xffffu) | (((uint32_t)(ha >> 32)) << 16);
        Hb[q0 + 1] = ((uint32_t)hb & 0xffffu) | (((uint32_t)(hb >> 32)) << 16);
        __syncthreads();

        // hk[m] = packed f16 pair (h[2(L+64m)], h[2(L+64m)+1])
        uint32_t hk[8];
#pragma unroll
        for (int m = 0; m < 8; ++m) hk[m] = Hb[L + 64 * m];

        // 8 row-dots via v_dot2_f32_f16 (rows rr = gate*2 + jj)
        float acc[8];
#pragma unroll
        for (int rr = 0; rr < 8; ++rr) {
            float a = 0.f;
#pragma unroll
            for (int m = 0; m < 8; ++m) a = dot2(wreg[rr][m], hk[m], a);
            acc[rr] = a;
        }

        // folded butterfly over bits {4,2,1}: lane L ends with row (L&7) partial
#pragma unroll
        for (int bit = 4; bit >= 1; bit >>= 1) {
#pragma unroll
            for (int i = 0; i < bit; ++i) {
                float v0 = acc[i], v1 = acc[i + bit];
                float send = (L & bit) ? v0 : v1;
                float recv = __shfl_xor(send, bit, 64);
                acc[i] = ((L & bit) ? v1 : v0) + recv;
            }
        }
        float tot = acc[0];
        tot += __shfl_xor(tot, 8, 64);
        tot += __shfl_xor(tot, 16, 64);
        tot += __shfl_xor(tot, 32, 64);
        // lane jj needs rows jj, 2+jj, 4+jj, 6+jj (held at lanes of those indices)
        float r0 = __shfl(tot, (L & 1), 64);
        float r1 = __shfl(tot, (L & 1) + 2, 64);
        float r2 = __shfl(tot, (L & 1) + 4, 64);
        float r3 = __shfl(tot, (L & 1) + 6, 64);

        // elementwise gate update on lanes 0,1 (jj = L); lane 0 publishes both units
        float gi = r0 + pxv[0];
        float gf = r1 + pxv[1];
        float gg = r2 + pxv[2];
        float go = r3 + pxv[3];
        float iv = fast_sig(gi);
        float fv = fast_sig(gf);
        float gv = fast_tanh(gg);
        float ov = fast_sig(go);
        c0 = fv * c0 + iv * gv;                     // meaningful on lanes 0,1 only
        float h = ov * fast_tanh(c0);
        uint32_t word = f16_bits(h) | ((uint32_t)(t + 1) << 16);
        uint32_t wd1 = (uint32_t)__shfl((int)word, 1, 64);
        float h1 = __shfl(h, 1, 64);
        if (L == 0) {
            // publish tagged h pair FIRST (critical path): one u64 store per wave
            uint64_t q = (uint64_t)word | ((uint64_t)wd1 << 32);
            __hip_atomic_store(dstb + (w * 4 + wave), q,
                               __ATOMIC_RELAXED, __HIP_MEMORY_SCOPE_AGENT);
            // then the f32 log (one float2 per wave)
            *(float2*)(lstm_out + (size_t)t * 1024 + w * 8 + 2 * wave) =
                make_float2(h, h1);
        }
    }
}

// ---------- log-softmax over axis 0 (columns of [8192][512]) ----------
__global__ void sm_partial(const float* __restrict__ logits, float* __restrict__ pM,
                           float* __restrict__ pS) {
    const int cb = blockIdx.x, rb = blockIdx.y, tid = threadIdx.x;
    const int c = cb * 64 + (tid & 63);
    const int r0 = rb * 256 + (tid >> 6) * 64;
    const float* p = logits + (size_t)r0 * 512 + c;
    float m = -1e30f;
    for (int k = 0; k < 64; ++k) m = fmaxf(m, p[(size_t)k * 512]);
    float s = 0.f;
    for (int k = 0; k < 64; ++k) s += __expf(p[(size_t)k * 512] - m);
    __shared__ float sM[4][64], sS[4][64];
    sM[tid >> 6][tid & 63] = m;
    sS[tid >> 6][tid & 63] = s;
    __syncthreads();
    if (tid < 64) {
        float M = sM[0][tid];
        for (int i = 1; i < 4; ++i) M = fmaxf(M, sM[i][tid]);
        float S = 0.f;
        for (int i = 0; i < 4; ++i) S += sS[i][tid] * __expf(sM[i][tid] - M);
        pM[rb * 512 + cb * 64 + tid] = M;
        pS[rb * 512 + cb * 64 + tid] = S;
    }
}

__global__ void sm_combine(const float* __restrict__ pM, const float* __restrict__ pS,
                           float* __restrict__ cc) {
    const int c = threadIdx.x;   // 512 threads
    float M = -1e30f;
    for (int i = 0; i < 32; ++i) M = fmaxf(M, pM[i * 512 + c]);
    float S = 0.f;
    for (int i = 0; i < 32; ++i) S += pS[i * 512 + c] * __expf(pM[i * 512 + c] - M);
    cc[c] = M + logf(S);
}

__global__ void sm_apply(float* __restrict__ out, const float* __restrict__ cc) {
    const int idx = blockIdx.x * 256 + threadIdx.x;    // float4 index, exactly 1M
    float4 v = ((const float4*)out)[idx];
    float4 b = ((const float4*)cc)[idx & 127];
    v.x -= b.x; v.y -= b.y; v.z -= b.z; v.w -= b.w;
    ((float4*)out)[idx] = v;
}

// ---------- launch ----------
extern "C" void kernel_launch(void* const* d_in, const int* in_sizes, int n_in,
                              void* d_out, int out_size, void* d_ws, size_t ws_size,
                              hipStream_t stream) {
    (void)in_sizes; (void)n_in; (void)out_size; (void)ws_size;
    const float* x    = (const float*)d_in[0];
    const float* Wih  = (const float*)d_in[1];
    const float* Whh  = (const float*)d_in[2];
    const float* bih  = (const float*)d_in[3];
    const float* bhh  = (const float*)d_in[4];
    const float* Wout = (const float*)d_in[5];
    const float* bout = (const float*)d_in[6];
    float* out = (float*)d_out;

    char* ws = (char*)d_ws;
    uint32_t* pxp   = (uint32_t*)(ws + 0ull);            // 8192*2048 words   (67,108,864 B)
    uint32_t* wpk   = (uint32_t*)(ws + 67108864ull);     // 128*32*512 words  ( 8,388,608 B)
    float* lstm_out = (float*)   (ws + 75497472ull);     // 8192*1024 f32     (33,554,432 B)
    float* biasc    = (float*)   (ws + 109051904ull);    // 4096 f32 (16 KB)
    uint32_t* htag  = (uint32_t*)(ws + 109068288ull);    // 2*1024 words (8 KB)
    float* pM       = (float*)   (ws + 109076480ull);    // 32*512 f32 (64 KB)
    float* pS       = (float*)   (ws + 109142016ull);    // 32*512 f32 (64 KB)
    float* cc       = (float*)   (ws + 109207552ull);    // 512 f32

    // deterministic per-call state: H[0] = 0 with tag 0
    hipMemsetAsync(htag, 0, 8192, stream);

    prep_whh<<<8192, 256, 0, stream>>>(Whh, wpk);
    prep_bias<<<16, 256, 0, stream>>>(bih, bhh, biasc);

    // px = x @ W_ih^T + (b_ih + b_hh), stored packed f16
    gemm_bt<true><<<dim3(64, 32), 256, 0, stream>>>(x, Wih, biasc, (void*)pxp, 4096, 1024);

    lstm_rec<<<NWG, 256, 0, stream>>>(wpk, pxp, htag, lstm_out);

    // logits = lstm_out @ W_out^T + b_out  -> d_out
    gemm_bt<false><<<dim3(64, 4), 256, 0, stream>>>(lstm_out, Wout, bout, (void*)out, 512, 1024);

    // log-softmax over sequence axis (columns)
    sm_partial<<<dim3(8, 32), 256, 0, stream>>>(out, pM, pS);
    sm_combine<<<1, 512, 0, stream>>>(pM, pS, cc);
    sm_apply<<<4096, 256, 0, stream>>>(out, cc);
}